// Round 5
// baseline (192.991 us; speedup 1.0000x reference)
//
#include <hip/hip_runtime.h>

// 5x5 normalized box blur, REFLECT_101, fp32, NCHW 32x3x512x512.
// Full-row waves: each wave = 64 lanes x 8 cols = one whole 512-col row.
// Horizontal halo via __shfl from neighbor lanes (no halo loads).
// Vertical 5-tap as running sum; RPT=4 output rows per thread, so the 4
// prologue h-rows are the only ones ever subtracted (no ring rotation).
// 3 raw rows (A/B/C) rolling => 3 row-loads (6 dwordx4) in flight per wave.
// Block: 4 waves -> 16-row full-width strip. Grid: 32 x 96 = 3072 blocks.

#define WID 512
#define HEI 512
#define RPT 4                 // output rows per thread
#define STRIP (4 * RPT)       // 16 rows per block (4 waves)

typedef float v4f __attribute__((ext_vector_type(4)));   // native clang vector

__global__ __launch_bounds__(256) void smooth_box5_kernel(
    const float* __restrict__ in, float* __restrict__ out)
{
    const int tid  = threadIdx.x;
    const int lane = tid & 63;
    const int wv   = tid >> 6;              // wave id 0..3
    const int c    = lane << 3;             // 8 cols per lane, wave covers 512
    const int r0   = blockIdx.x * STRIP + wv * RPT;
    const long long plane = blockIdx.y;

    const float* __restrict__ ip = in  + plane * (long long)(HEI * WID);
    float*       __restrict__ op = out + plane * (long long)(HEI * WID);

    const bool Ledge = (lane == 0);
    const bool Redge = (lane == 63);

    // Load one full input row segment (8 cols) as two v4f. REFLECT_101 rows.
    auto loadraw = [&](int gy, v4f& m0, v4f& m1) {
        gy = (gy < 0) ? -gy : ((gy >= HEI) ? (2 * HEI - 2 - gy) : gy);
        const float* row = ip + gy * WID + c;
        m0 = *reinterpret_cast<const v4f*>(row);
        m1 = *reinterpret_cast<const v4f*>(row + 4);
    };

    // Horizontal 5-tap sums (unnormalized) for this lane's 8 columns.
    // Halo cols c-2,c-1 / c+8,c+9 come from neighbor lanes via shfl.
    auto hsum = [&](const v4f m0, const v4f m1, float h[8]) {
        float lx = __shfl_up(m1.z, 1);      // lane-1: col c-2
        float ly = __shfl_up(m1.w, 1);      // c-1
        float rx = __shfl_down(m0.x, 1);    // lane+1: col c+8
        float ry = __shfl_down(m0.y, 1);    // c+9
        if (Ledge) { lx = m0.z; ly = m0.y; }    // cols -2,-1 -> 2,1
        if (Redge) { rx = m1.z; ry = m1.y; }    // cols 512,513 -> 510,509
        float a[12] = { lx, ly, m0.x, m0.y, m0.z, m0.w,
                        m1.x, m1.y, m1.z, m1.w, rx, ry };
        float t[11];
        #pragma unroll
        for (int j = 0; j < 11; ++j) t[j] = a[j] + a[j + 1];
        #pragma unroll
        for (int j = 0; j < 8; ++j) h[j] = t[j] + t[j + 2] + a[j + 4];
    };

    auto storerow = [&](float* p, const float vsum[8]) {
        v4f o0 = { vsum[0]*0.04f, vsum[1]*0.04f, vsum[2]*0.04f, vsum[3]*0.04f };
        v4f o1 = { vsum[4]*0.04f, vsum[5]*0.04f, vsum[6]*0.04f, vsum[7]*0.04f };
        __builtin_nontemporal_store(o0, reinterpret_cast<v4f*>(p));
        __builtin_nontemporal_store(o1, reinterpret_cast<v4f*>(p + 4));
    };

    v4f A0, A1, B0, B1, C0, C1;
    float h[4][8];     // rows r0-2 .. r0+1 (the only rows ever subtracted)
    float hn[8];       // scratch for rows r0+2 .. r0+5
    float vs[8];

    // Prologue: keep 3 row-loads in flight at all times.
    loadraw(r0 - 2, A0, A1);
    loadraw(r0 - 1, B0, B1);
    loadraw(r0,     C0, C1);
    hsum(A0, A1, h[0]); loadraw(r0 + 1, A0, A1);
    hsum(B0, B1, h[1]); loadraw(r0 + 2, B0, B1);
    hsum(C0, C1, h[2]); loadraw(r0 + 3, C0, C1);
    hsum(A0, A1, h[3]); loadraw(r0 + 4, A0, A1);

    #pragma unroll
    for (int j = 0; j < 8; ++j)
        vs[j] = h[0][j] + h[1][j] + h[2][j] + h[3][j];

    float* orow = op + (long long)r0 * WID + c;

    // k = 0: window rows r0-2..r0+2 ; new row r0+2 is in B
    hsum(B0, B1, hn); loadraw(r0 + 5, B0, B1);
    #pragma unroll
    for (int j = 0; j < 8; ++j) vs[j] += hn[j];
    storerow(orow, vs);
    #pragma unroll
    for (int j = 0; j < 8; ++j) vs[j] -= h[0][j];
    orow += WID;

    // k = 1: new row r0+3 in C
    hsum(C0, C1, hn);
    #pragma unroll
    for (int j = 0; j < 8; ++j) vs[j] += hn[j];
    storerow(orow, vs);
    #pragma unroll
    for (int j = 0; j < 8; ++j) vs[j] -= h[1][j];
    orow += WID;

    // k = 2: new row r0+4 in A
    hsum(A0, A1, hn);
    #pragma unroll
    for (int j = 0; j < 8; ++j) vs[j] += hn[j];
    storerow(orow, vs);
    #pragma unroll
    for (int j = 0; j < 8; ++j) vs[j] -= h[2][j];
    orow += WID;

    // k = 3: new row r0+5 in B
    hsum(B0, B1, hn);
    #pragma unroll
    for (int j = 0; j < 8; ++j) vs[j] += hn[j];
    storerow(orow, vs);
}

extern "C" void kernel_launch(void* const* d_in, const int* in_sizes, int n_in,
                              void* d_out, int out_size, void* d_ws, size_t ws_size,
                              hipStream_t stream) {
    const float* img = (const float*)d_in[0];
    float* out = (float*)d_out;
    // Shapes fixed by the reference: (32, 3, 512, 512), w = 5.
    const int B = 32, C = 3;
    dim3 grid(HEI / STRIP, B * C);   // 32 x 96 = 3072 blocks
    dim3 block(256);
    smooth_box5_kernel<<<grid, block, 0, stream>>>(img, out);
}

// Round 6
// 176.584 us; speedup vs baseline: 1.0929x; 1.0929x over previous
//
#include <hip/hip_runtime.h>

// 5x5 normalized box blur, REFLECT_101, fp32, NCHW 32x3x512x512.
// Full-row waves with DENSE lane mapping: lane owns cols lane*4 (half 0)
// and 256+lane*4 (half 1). Every global load/store instruction is a
// contiguous fully-dense 1KB wave transaction (16 full 64B lines) --
// no partial-line writes (R5's WRITE_SIZE showed 1.48x RMW inflation
// with the 32B-stride mapping + nontemporal).
// Horizontal halo entirely in-wave: shfl_up/down within each half,
// rotate-shfl with pre-select across the col-256 seam, cndmask reflect
// at the image edges. Vertical 5-tap = running sum, RPT=4 rows/thread.
// 3 raw rows (A/B/C) rolling => 6 dwordx4 loads in flight per wave.
// Block: 4 waves -> 16-row full-width strip. Grid: 32 x 96 = 3072 blocks.

#define WID 512
#define HEI 512
#define RPT 4                 // output rows per thread
#define STRIP (4 * RPT)       // 16 rows per block (4 waves)

typedef float v4f __attribute__((ext_vector_type(4)));

__global__ __launch_bounds__(256) void smooth_box5_kernel(
    const float* __restrict__ in, float* __restrict__ out)
{
    const int tid  = threadIdx.x;
    const int lane = tid & 63;
    const int wv   = tid >> 6;              // wave id 0..3
    const int r0   = blockIdx.x * STRIP + wv * RPT;
    const long long plane = blockIdx.y;

    const float* __restrict__ ip = in  + plane * (long long)(HEI * WID);
    float*       __restrict__ op = out + plane * (long long)(HEI * WID);

    const int cA = lane * 4;                // half 0: cols 0..255, dense
    const int cB = 256 + lane * 4;          // half 1: cols 256..511, dense
    const int up1 = (lane + 63) & 63;       // rotate: pull from lane-1
    const int dn1 = (lane + 1) & 63;        // rotate: pull from lane+1
    const bool l0  = (lane == 0);
    const bool l63 = (lane == 63);

    // Load one full input row: two dense 1KB wave transactions.
    auto loadraw = [&](int gy, v4f& a, v4f& b) {
        gy = (gy < 0) ? -gy : ((gy >= HEI) ? (2 * HEI - 2 - gy) : gy);
        const float* row = ip + gy * WID;
        a = *reinterpret_cast<const v4f*>(row + cA);
        b = *reinterpret_cast<const v4f*>(row + cB);
    };

    // Horizontal 5-tap sums (unnormalized): h[0..3] for cols cA..cA+3,
    // h[4..7] for cols cB..cB+3.
    auto hsum = [&](const v4f a, const v4f b, float h[8]) {
        // half0 left halo: cols cA-2, cA-1
        float lA0 = __shfl_up(a.z, 1);                 // lane0: own a.z = col2 (reflect of -2)
        float lA1 = __shfl_up(a.w, 1);
        lA1 = l0 ? a.y : lA1;                          // lane0: col -1 -> col 1
        // half0 right halo: cols cA+4, cA+5 (lane63 crosses seam -> b.x/b.y of lane0)
        float sx = l0 ? b.x : a.x;
        float sy = l0 ? b.y : a.y;
        float rA0 = __shfl(sx, dn1);
        float rA1 = __shfl(sy, dn1);
        // half1 left halo: cols cB-2, cB-1 (lane0 crosses seam -> a.z/a.w of lane63)
        float sz = l63 ? a.z : b.z;
        float sw = l63 ? a.w : b.w;
        float lB0 = __shfl(sz, up1);
        float lB1 = __shfl(sw, up1);
        // half1 right halo: cols cB+4, cB+5
        float rB0 = __shfl_down(b.x, 1);
        rB0 = l63 ? b.z : rB0;                         // col 512 -> col 510
        float rB1 = __shfl_down(b.y, 1);               // lane63: own b.y = col 509 (reflect of 513)

        float e0[8] = { lA0, lA1, a.x, a.y, a.z, a.w, rA0, rA1 };
        float e1[8] = { lB0, lB1, b.x, b.y, b.z, b.w, rB0, rB1 };
        float t0[6], t1[6];
        #pragma unroll
        for (int j = 0; j < 6; ++j) { t0[j] = e0[j] + e0[j + 1]; t1[j] = e1[j] + e1[j + 1]; }
        #pragma unroll
        for (int j = 0; j < 4; ++j) {
            h[j]     = t0[j] + t0[j + 2] + e0[j + 4];
            h[4 + j] = t1[j] + t1[j + 2] + e1[j + 4];
        }
    };

    auto storerow = [&](float* p, const float vsum[8]) {
        v4f o0 = { vsum[0]*0.04f, vsum[1]*0.04f, vsum[2]*0.04f, vsum[3]*0.04f };
        v4f o1 = { vsum[4]*0.04f, vsum[5]*0.04f, vsum[6]*0.04f, vsum[7]*0.04f };
        *reinterpret_cast<v4f*>(p + cA) = o0;          // dense 1KB
        *reinterpret_cast<v4f*>(p + cB) = o1;          // dense 1KB
    };

    v4f A0, A1, B0, B1, C0, C1;
    float h[4][8];     // rows r0-2 .. r0+1 (the only rows ever subtracted)
    float hn[8];       // scratch for rows r0+2 .. r0+5
    float vs[8];

    // Prologue: keep 3 row-loads in flight at all times.
    loadraw(r0 - 2, A0, A1);
    loadraw(r0 - 1, B0, B1);
    loadraw(r0,     C0, C1);
    hsum(A0, A1, h[0]); loadraw(r0 + 1, A0, A1);
    hsum(B0, B1, h[1]); loadraw(r0 + 2, B0, B1);
    hsum(C0, C1, h[2]); loadraw(r0 + 3, C0, C1);
    hsum(A0, A1, h[3]); loadraw(r0 + 4, A0, A1);

    #pragma unroll
    for (int j = 0; j < 8; ++j)
        vs[j] = h[0][j] + h[1][j] + h[2][j] + h[3][j];

    float* orow = op + (long long)r0 * WID;

    // k = 0: window rows r0-2..r0+2 ; new row r0+2 is in B
    hsum(B0, B1, hn); loadraw(r0 + 5, B0, B1);
    #pragma unroll
    for (int j = 0; j < 8; ++j) vs[j] += hn[j];
    storerow(orow, vs);
    #pragma unroll
    for (int j = 0; j < 8; ++j) vs[j] -= h[0][j];
    orow += WID;

    // k = 1: new row r0+3 in C
    hsum(C0, C1, hn);
    #pragma unroll
    for (int j = 0; j < 8; ++j) vs[j] += hn[j];
    storerow(orow, vs);
    #pragma unroll
    for (int j = 0; j < 8; ++j) vs[j] -= h[1][j];
    orow += WID;

    // k = 2: new row r0+4 in A
    hsum(A0, A1, hn);
    #pragma unroll
    for (int j = 0; j < 8; ++j) vs[j] += hn[j];
    storerow(orow, vs);
    #pragma unroll
    for (int j = 0; j < 8; ++j) vs[j] -= h[2][j];
    orow += WID;

    // k = 3: new row r0+5 in B
    hsum(B0, B1, hn);
    #pragma unroll
    for (int j = 0; j < 8; ++j) vs[j] += hn[j];
    storerow(orow, vs);
}

extern "C" void kernel_launch(void* const* d_in, const int* in_sizes, int n_in,
                              void* d_out, int out_size, void* d_ws, size_t ws_size,
                              hipStream_t stream) {
    const float* img = (const float*)d_in[0];
    float* out = (float*)d_out;
    // Shapes fixed by the reference: (32, 3, 512, 512), w = 5.
    const int B = 32, C = 3;
    dim3 grid(HEI / STRIP, B * C);   // 32 x 96 = 3072 blocks
    dim3 block(256);
    smooth_box5_kernel<<<grid, block, 0, stream>>>(img, out);
}